// Round 5
// baseline (181.865 us; speedup 1.0000x reference)
//
#include <hip/hip_runtime.h>
#include <cmath>
#include <complex>

// sr=16000, band 500-7000, order 8 -> 16 poles (8 conjugate pairs).
#define NB   32
#define LX   262144
#define PAD  51                       // padlen = 3*17
#define LTOT (LX + 2 * PAD)           // 262246
#define CM   32                       // chunk length
#define NC   8196                     // ceil(LTOT/CM)
#define LPAD (NC * CM)                // 262272 (26 pad slots at reversed head)
#define CPB  256
#define BPR  ((NC + CPB - 1) / CPB)   // 33
#define NP   8
#define JSEG ((NC + 255) / 256)       // 33 chunks per scan thread

// table float offsets (in d_ws tail)
#define T_H   0                       // h[32]   FIR taps (impulse response)
#define T_CR  32                      // cstR[8][32] = Re(r*p^(31-i))
#define T_CI  288                     // cstI[8][32]
#define T_AR  544                     // AR[8][32]   = Re(p^(i+1))
#define T_AI  800                     // AI[8][32]   = Im(p^(i+1))
#define T_N   1056

struct CoeffsD { double pre[NP], pim[NP], rre[NP], rim[NP], c0; };
struct ScanF {
    float pmre[NP], pmim[NP];         // p^CM
    float qre[8][NP], qim[8][NP];     // (p^(CM*JSEG))^(2^k)
    float gre[NP], gim[NP];           // r2*(1-p^CM)/(1-p)  (base correction)
};

// Setup: build f32 tables from f64 pole data on device (graph-capture safe).
__global__ void k_tables(float* __restrict__ tbl, CoeffsD D) {
    int t = threadIdx.x;              // 256 threads: q = t>>5, i = t&31
    int q = t >> 5, i = t & 31;
    double Pre = D.pre[q], Pim = D.pim[q];
    double pr = 1.0, pi_ = 0.0;       // p^i
    for (int k = 0; k < i; k++) {
        double nr = pr * Pre - pi_ * Pim, ni = pr * Pim + pi_ * Pre;
        pr = nr; pi_ = ni;
    }
    double qr = 1.0, qi = 0.0;        // p^(31-i)
    for (int k = 0; k < 31 - i; k++) {
        double nr = qr * Pre - qi * Pim, ni = qr * Pim + qi * Pre;
        qr = nr; qi = ni;
    }
    tbl[T_CR + q * 32 + i] = (float)(D.rre[q] * qr - D.rim[q] * qi);
    tbl[T_CI + q * 32 + i] = (float)(D.rre[q] * qi + D.rim[q] * qr);
    double ar = pr * Pre - pi_ * Pim, ai = pr * Pim + pi_ * Pre;   // p^(i+1)
    tbl[T_AR + q * 32 + i] = (float)ar;
    tbl[T_AI + q * 32 + i] = (float)ai;
    if (q == 0) {                     // h[i] = c0*d(i) + sum_q Re(r_q p_q^i)
        double hv = (i == 0) ? D.c0 : 0.0;
        for (int qq = 0; qq < NP; qq++) {
            double xr = 1.0, xi = 0.0;
            for (int k = 0; k < i; k++) {
                double nr = xr * D.pre[qq] - xi * D.pim[qq];
                double ni = xr * D.pim[qq] + xi * D.pre[qq];
                xr = nr; xi = ni;
            }
            hv += D.rre[qq] * xr - D.rim[qq] * xi;
        }
        tbl[T_H + i] = (float)hv;
    }
}

// u[t] = ext[t] - ext[0] for the forward pass (odd extension of audio).
__device__ __forceinline__ void load_u_fwd(const float* __restrict__ x,
                                           float base, int t0, float (&u)[CM]) {
    if (t0 >= PAD && t0 + CM <= PAD + LX) {
        const float* xs = x + (t0 - PAD);
#pragma unroll
        for (int m = 0; m < CM / 4; m++) {
            float4 v = *reinterpret_cast<const float4*>(xs + 4 * m);
            u[4 * m] = v.x - base; u[4 * m + 1] = v.y - base;
            u[4 * m + 2] = v.z - base; u[4 * m + 3] = v.w - base;
        }
    } else {
#pragma unroll
        for (int i = 0; i < CM; i++) {
            int t = t0 + i;
            float e;
            if (t < PAD)            e = 2.0f * x[0] - x[PAD - t];
            else if (t < PAD + LX)  e = x[t - PAD];
            else if (t < LTOT)      e = 2.0f * x[LX - 1] - x[2 * LX + PAD - 2 - t];
            else                    e = base;   // u=0 tail continuation
            u[i] = e - base;
        }
    }
}

// K1: pass-A local chunk states via FIR dot (no serial chain).
__global__ __launch_bounds__(256) void k_statesA(const float* __restrict__ audio,
                                                 float2* __restrict__ fst,
                                                 const float* __restrict__ tbl) {
    int c = blockIdx.x * CPB + threadIdx.x, b = blockIdx.y;
    if (c >= NC) return;
    const float* x = audio + (size_t)b * LX;
    float base = 2.0f * x[0] - x[PAD];
    float u[CM];
    load_u_fwd(x, base, c * CM, u);
    float sre[NP], sim[NP];
#pragma unroll
    for (int q = 0; q < NP; q++) { sre[q] = 0.f; sim[q] = 0.f; }
#pragma unroll
    for (int i = 0; i < CM; i++) {
        float uu = u[i];
#pragma unroll
        for (int q = 0; q < NP; q++) {
            sre[q] = fmaf(tbl[T_CR + q * 32 + i], uu, sre[q]);
            sim[q] = fmaf(tbl[T_CI + q * 32 + i], uu, sim[q]);
        }
    }
#pragma unroll
    for (int q = 0; q < NP; q++)
        fst[(size_t)(b * NP + q) * NC + c] = make_float2(sre[q], sim[q]);
}

// K2: hierarchical affine scan, in-place states -> carries.
// CORR=1 (pass B): logical idx -> physical slot NC-1-idx; subtract base*G.
template <int CORR>
__global__ __launch_bounds__(256) void k_scan(float2* __restrict__ fc,
                                              const float* __restrict__ ybuf, ScanF S) {
    int blk = blockIdx.x, q = blk % NP, b = blk / NP, t = threadIdx.x;
    float pre = S.pmre[q], pim = S.pmim[q];
    float cgr = 0.f, cgi = 0.f;
    if (CORR) {
        float base = ybuf[(size_t)b * LPAD + 26];
        cgr = base * S.gre[q]; cgi = base * S.gim[q];
    }
    float2* f = fc + (size_t)blk * NC;
    float sre = 0.f, sim = 0.f;
    for (int j = 0; j < JSEG; j++) {
        int c = t * JSEG + j;
        if (c < NC) {
            float2 v = f[CORR ? (NC - 1 - c) : c];
            float nre = fmaf(pre, sre, fmaf(-pim, sim, v.x - cgr));
            float nim = fmaf(pre, sim, fmaf( pim, sre, v.y - cgi));
            sre = nre; sim = nim;
        }
    }
    __shared__ float2 sc[256];
    sc[t] = make_float2(sre, sim);
    __syncthreads();
#pragma unroll
    for (int k = 0; k < 8; k++) {
        int d = 1 << k;
        float2 o = (t >= d) ? sc[t - d] : make_float2(0.f, 0.f);
        __syncthreads();
        if (t >= d) {
            float qr = S.qre[k][q], qi = S.qim[k][q];
            sre = fmaf(qr, o.x, fmaf(-qi, o.y, sre));
            sim = fmaf(qr, o.y, fmaf( qi, o.x, sim));
        }
        sc[t] = make_float2(sre, sim);
        __syncthreads();
    }
    float2 e = (t == 0) ? make_float2(0.f, 0.f) : sc[t - 1];
    float s2re = e.x, s2im = e.y;
    for (int j = 0; j < JSEG; j++) {
        int c = t * JSEG + j;
        if (c < NC) {
            int s = CORR ? (NC - 1 - c) : c;
            float2 v = f[s];
            f[s] = make_float2(s2re, s2im);      // carry entering logical chunk c
            float nre = fmaf(pre, s2re, fmaf(-pim, s2im, v.x - cgr));
            float nim = fmaf(pre, s2im, fmaf( pim, s2re, v.y - cgi));
            s2re = nre; s2im = nim;
        }
    }
}

// K3 (fused): y = FIR(u) + carry-response(S0); write y reversed into ybuf;
// then pass-B local states (FIR dot over reversed y) in-place over slot c.
__global__ __launch_bounds__(256) void k_fusedA(const float* __restrict__ audio,
                                                float2* __restrict__ fst,
                                                float* __restrict__ ybuf,
                                                const float* __restrict__ tbl) {
    int c = blockIdx.x * CPB + threadIdx.x, b = blockIdx.y;
    if (c >= NC) return;
    const float* x = audio + (size_t)b * LX;
    float base = 2.0f * x[0] - x[PAD];
    float buf[CM];
    load_u_fwd(x, base, c * CM, buf);
    float s0r[NP], s0i[NP];
#pragma unroll
    for (int q = 0; q < NP; q++) {
        float2 s0 = fst[(size_t)(b * NP + q) * NC + c];
        s0r[q] = s0.x; s0i[q] = s0.y;
    }
    // acc[i] = carry response = sum_q Re(p^(i+1)) s0r - Im(p^(i+1)) s0i
    float acc[CM];
#pragma unroll
    for (int i = 0; i < CM; i++) {
        float v = 0.f;
#pragma unroll
        for (int q = 0; q < NP; q++) {
            v = fmaf(tbl[T_AR + q * 32 + i], s0r[q], v);
            v = fmaf(tbl[T_AI + q * 32 + i], -s0i[q], v);
        }
        acc[i] = v;
    }
    // triangular FIR; buf[j] becomes final y[j] when its inputs are consumed
#pragma unroll
    for (int j = 0; j < CM; j++) {
        float uj = buf[j];
#pragma unroll
        for (int i = j; i < CM; i++)
            acc[i] = fmaf(tbl[T_H + (i - j)], uj, acc[i]);
        buf[j] = acc[j];
    }
    // reversed aligned write: ybuf[(NC-1-c)*CM + i] = y[31-i]
    float* yb = ybuf + (size_t)b * LPAD + (size_t)(NC - 1 - c) * CM;
#pragma unroll
    for (int m = 0; m < CM / 4; m++) {
        float4 v = make_float4(buf[CM - 1 - 4 * m], buf[CM - 2 - 4 * m],
                               buf[CM - 3 - 4 * m], buf[CM - 4 - 4 * m]);
        *reinterpret_cast<float4*>(yb + 4 * m) = v;
    }
    // pass-B local states for chunk cp=NC-1-c (FIR dot over reversed y).
    // c==NC-1 (cp==0): samples i<26 are pad -> input := base2 = y[LTOT-1].
    float base2 = buf[5];
    bool last = (c == NC - 1);
    float tre[NP], tim[NP];
#pragma unroll
    for (int q = 0; q < NP; q++) { tre[q] = 0.f; tim[q] = 0.f; }
#pragma unroll
    for (int i = 0; i < CM; i++) {
        float wv = buf[CM - 1 - i];
        if (last && i < 26) wv = base2;
#pragma unroll
        for (int q = 0; q < NP; q++) {
            tre[q] = fmaf(tbl[T_CR + q * 32 + i], wv, tre[q]);
            tim[q] = fmaf(tbl[T_CI + q * 32 + i], wv, tim[q]);
        }
    }
#pragma unroll
    for (int q = 0; q < NP; q++)
        fst[(size_t)(b * NP + q) * NC + c] = make_float2(tre[q], tim[q]);
}

// K4: pass-B replay via FIR + carry response -> final output (rev + trim).
__global__ __launch_bounds__(256) void k_applyB(const float* __restrict__ ybuf,
                                                const float2* __restrict__ carry,
                                                float* __restrict__ out,
                                                const float* __restrict__ tbl) {
    int cp = blockIdx.x * CPB + threadIdx.x, b = blockIdx.y;
    if (cp >= NC) return;
    const float* yb = ybuf + (size_t)b * LPAD;
    float base = yb[26];
    float buf[CM];
#pragma unroll
    for (int m = 0; m < CM / 4; m++) {
        float4 v = *reinterpret_cast<const float4*>(yb + (size_t)cp * CM + 4 * m);
        buf[4 * m] = v.x - base; buf[4 * m + 1] = v.y - base;
        buf[4 * m + 2] = v.z - base; buf[4 * m + 3] = v.w - base;
    }
    float s0r[NP], s0i[NP];
#pragma unroll
    for (int q = 0; q < NP; q++) {
        float2 s0 = carry[(size_t)(b * NP + q) * NC + (NC - 1 - cp)];
        s0r[q] = s0.x; s0i[q] = s0.y;
    }
    float acc[CM];
#pragma unroll
    for (int i = 0; i < CM; i++) {
        float v = 0.f;
#pragma unroll
        for (int q = 0; q < NP; q++) {
            v = fmaf(tbl[T_AR + q * 32 + i], s0r[q], v);
            v = fmaf(tbl[T_AI + q * 32 + i], -s0i[q], v);
        }
        acc[i] = v;
    }
#pragma unroll
    for (int j = 0; j < CM; j++) {
        float uj = buf[j];
#pragma unroll
        for (int i = j; i < CM; i++)
            acc[i] = fmaf(tbl[T_H + (i - j)], uj, acc[i]);
        buf[j] = acc[j];
    }
    // out[j] = buf[i], j = 262220 - 32*cp - i; jb == 1 mod 4
    float* ob = out + (size_t)b * LX;
    int jb = (LTOT - 1 - PAD + 26 - 31) - cp * CM;   // 262189 - 32*cp
    if (jb >= 0 && jb + 31 < LX) {
        ob[jb] = buf[31]; ob[jb + 1] = buf[30]; ob[jb + 2] = buf[29];
        ob[jb + 31] = buf[0];
#pragma unroll
        for (int g = 0; g < 7; g++) {
            float4 v = make_float4(buf[28 - 4 * g], buf[27 - 4 * g],
                                   buf[26 - 4 * g], buf[25 - 4 * g]);
            *reinterpret_cast<float4*>(ob + jb + 3 + 4 * g) = v;
        }
    } else {
#pragma unroll
        for (int i = 0; i < CM; i++) {
            int j = jb + 31 - i;
            if (j >= 0 && j < LX) ob[j] = buf[i];
        }
    }
}

// Host: scipy butter(8,[500,7000]/8000,'bandpass') -> poles/residues (f64).
static void compute_coeffs(CoeffsD& D, ScanF& S) {
    using cd = std::complex<double>;
    const int N = 8;
    const double sr = 16000.0, lo = 500.0, hi = 7000.0, fs = 2.0;
    double w0 = 2.0 * fs * std::tan(M_PI * (2.0 * lo / sr) / fs);
    double w1 = 2.0 * fs * std::tan(M_PI * (2.0 * hi / sr) / fs);
    double bw = w1 - w0, wo = std::sqrt(w0 * w1);
    cd pbp[16];
    for (int k = 0; k < N; k++) {
        int m = -N + 1 + 2 * k;
        cd pl = -std::exp(cd(0.0, M_PI * m / (2.0 * N)));
        pl *= bw / 2.0;
        cd s = std::sqrt(pl * pl - cd(wo * wo, 0.0));
        pbp[k] = pl + s; pbp[k + N] = pl - s;
    }
    double kbp = std::pow(bw, (double)N);
    const double fs2 = 4.0;
    cd pd[16], denom = 1.0;
    for (int i = 0; i < 16; i++) {
        pd[i] = (cd(fs2, 0.0) + pbp[i]) / (cd(fs2, 0.0) - pbp[i]);
        denom *= (cd(fs2, 0.0) - pbp[i]);
    }
    double kd = kbp * std::real(cd(std::pow(fs2, 8.0), 0.0) / denom);
    cd prodp = 1.0;
    for (int i = 0; i < 16; i++) prodp *= pd[i];
    cd c0 = cd(kd, 0.0) / prodp;
    int n = 0;
    for (int i = 0; i < 16; i++) {
        if (pd[i].imag() <= 0.0) continue;
        cd inv = 1.0 / pd[i];
        cd t1 = cd(1.0, 0.0) - inv, t2 = cd(1.0, 0.0) + inv;
        cd numr = cd(kd, 0.0);
        for (int k = 0; k < 8; k++) numr *= t1;
        for (int k = 0; k < 8; k++) numr *= t2;
        cd den = 1.0;
        for (int j = 0; j < 16; j++)
            if (j != i) den *= (cd(1.0, 0.0) - pd[j] * inv);
        cd r2 = 2.0 * numr / den;                     // conjugate-pair folded
        cd pm = 1.0;
        for (int k = 0; k < CM; k++) pm *= pd[i];     // p^CM
        cd G = r2 * (cd(1.0, 0.0) - pm) / (cd(1.0, 0.0) - pd[i]);
        if (n < NP) {
            D.pre[n] = pd[i].real(); D.pim[n] = pd[i].imag();
            D.rre[n] = r2.real();    D.rim[n] = r2.imag();
            S.pmre[n] = (float)pm.real();   S.pmim[n] = (float)pm.imag();
            S.gre[n] = (float)G.real();     S.gim[n] = (float)G.imag();
            cd qv = 1.0;
            for (int k = 0; k < JSEG; k++) qv *= pm;  // p^(CM*JSEG)
            for (int k = 0; k < 8; k++) {
                S.qre[k][n] = (float)qv.real(); S.qim[k][n] = (float)qv.imag();
                qv *= qv;
            }
            n++;
        }
    }
    D.c0 = c0.real();
}

extern "C" void kernel_launch(void* const* d_in, const int* in_sizes, int n_in,
                              void* d_out, int out_size, void* d_ws, size_t ws_size,
                              hipStream_t stream) {
    const float* audio = (const float*)d_in[0];
    float* out = (float*)d_out;

    CoeffsD D; ScanF S;
    compute_coeffs(D, S);

    // ws: ybuf (NB*LPAD f32, 33.57MB) + fst (256*NC float2, 16.79MB, in-place
    // states->carries both passes) + tbl (4.2KB). Total ~50.4MB.
    char* ws = (char*)d_ws;
    size_t ybytes = (size_t)NB * LPAD * sizeof(float);
    size_t fbytes = (size_t)NB * NP * NC * sizeof(float2);
    float*  ybuf = (float*)ws;
    float2* fst  = (float2*)(ws + ybytes);
    float*  tbl  = (float*)(ws + ybytes + fbytes);

    dim3 blk(256), g(BPR, NB), gs(NB * NP);

    k_tables  <<<1,  256, 0, stream>>>(tbl, D);
    k_statesA <<<g,  blk, 0, stream>>>(audio, fst, tbl);
    k_scan<0> <<<gs, blk, 0, stream>>>(fst, ybuf, S);
    k_fusedA  <<<g,  blk, 0, stream>>>(audio, fst, ybuf, tbl);
    k_scan<1> <<<gs, blk, 0, stream>>>(fst, ybuf, S);
    k_applyB  <<<g,  blk, 0, stream>>>(ybuf, fst, out, tbl);
}

// Round 6
// 131.320 us; speedup vs baseline: 1.3849x; 1.3849x over previous
//
#include <hip/hip_runtime.h>
#include <cmath>
#include <complex>

// sr=16000, band 500-7000, order 8 -> 16 poles = 8 real 2nd-order sections.
#define NB   32
#define LX   262144
#define PAD  51                       // padlen = 3*17
#define LTOT (LX + 2 * PAD)           // 262246
#define CM   32                       // chunk length
#define NC   8196                     // ceil(LTOT/CM)
#define LPAD (NC * CM)                // 262272 (26 pad slots at reversed head)
#define CPB  256
#define BPR  ((NC + CPB - 1) / CPB)   // 33
#define NP   8
#define JSEG ((NC + 255) / 256)       // 33 chunks per scan thread
#define LDS_STRIDE 34                 // floats per LDS row (2-way-free b64)

struct CoeffsS { float a1[NP], a2[NP], b0[NP], b1[NP], c0; };
struct ScanS {
    float m00[NP], m01[NP], m10[NP], m11[NP];          // M = A^CM (2x2)
    float q00[8][NP], q01[8][NP], q10[8][NP], q11[8][NP]; // (M^JSEG)^(2^k)
    float g1[NP], g2[NP];                              // const-input response
};

// u[t] = ext[t] - ext[0] for the forward pass (odd extension of audio).
__device__ __forceinline__ void load_u_fwd(const float* __restrict__ x,
                                           float base, int t0, float (&u)[CM]) {
    if (t0 >= PAD && t0 + CM <= PAD + LX) {
        const float* xs = x + (t0 - PAD);
#pragma unroll
        for (int m = 0; m < CM / 4; m++) {
            float4 v = *reinterpret_cast<const float4*>(xs + 4 * m);
            u[4 * m] = v.x - base; u[4 * m + 1] = v.y - base;
            u[4 * m + 2] = v.z - base; u[4 * m + 3] = v.w - base;
        }
    } else {
#pragma unroll
        for (int i = 0; i < CM; i++) {
            int t = t0 + i;
            float e;
            if (t < PAD)            e = 2.0f * x[0] - x[PAD - t];
            else if (t < PAD + LX)  e = x[t - PAD];
            else if (t < LTOT)      e = 2.0f * x[LX - 1] - x[2 * LX + PAD - 2 - t];
            else                    e = base;   // u=0 tail continuation
            u[i] = e - base;
        }
    }
}

// K1: pass-A local chunk-final states (w_last, w_last-1) from zero init.
__global__ __launch_bounds__(256, 4) void k_statesA(const float* __restrict__ audio,
                                                    float2* __restrict__ fst, CoeffsS C) {
    int c = blockIdx.x * CPB + threadIdx.x, b = blockIdx.y;
    if (c >= NC) return;
    const float* x = audio + (size_t)b * LX;
    float base = 2.0f * x[0] - x[PAD];
    float u[CM];
    load_u_fwd(x, base, c * CM, u);
    float w1[NP], w2[NP];
#pragma unroll
    for (int q = 0; q < NP; q++) { w1[q] = 0.f; w2[q] = 0.f; }
#pragma unroll
    for (int i = 0; i < CM; i++) {
        float uu = u[i];
#pragma unroll
        for (int q = 0; q < NP; q++) {
            float wt = fmaf(C.a1[q], w1[q], fmaf(C.a2[q], w2[q], uu));
            w2[q] = w1[q]; w1[q] = wt;
        }
    }
#pragma unroll
    for (int q = 0; q < NP; q++)
        fst[(size_t)(b * NP + q) * NC + c] = make_float2(w1[q], w2[q]);
}

// K2: hierarchical affine scan (2x2 real matrices), in-place states->carries.
// CORR=1 (pass B): logical idx -> physical slot NC-1-idx; subtract base*g.
template <int CORR>
__global__ __launch_bounds__(256) void k_scan(float2* __restrict__ fc,
                                              const float* __restrict__ ybuf, ScanS S) {
    int blk = blockIdx.x, q = blk % NP, b = blk / NP, t = threadIdx.x;
    float m00 = S.m00[q], m01 = S.m01[q], m10 = S.m10[q], m11 = S.m11[q];
    float cg1 = 0.f, cg2 = 0.f;
    if (CORR) {
        float base = ybuf[(size_t)b * LPAD + 26];
        cg1 = base * S.g1[q]; cg2 = base * S.g2[q];
    }
    float2* f = fc + (size_t)blk * NC;
    float s1 = 0.f, s2 = 0.f;
    for (int j = 0; j < JSEG; j++) {
        int c = t * JSEG + j;
        if (c < NC) {
            float2 v = f[CORR ? (NC - 1 - c) : c];
            float n1 = fmaf(m00, s1, fmaf(m01, s2, v.x - cg1));
            float n2 = fmaf(m10, s1, fmaf(m11, s2, v.y - cg2));
            s1 = n1; s2 = n2;
        }
    }
    __shared__ float2 sc[256];
    sc[t] = make_float2(s1, s2);
    __syncthreads();
#pragma unroll
    for (int k = 0; k < 8; k++) {
        int d = 1 << k;
        float2 o = (t >= d) ? sc[t - d] : make_float2(0.f, 0.f);
        __syncthreads();
        if (t >= d) {
            s1 = fmaf(S.q00[k][q], o.x, fmaf(S.q01[k][q], o.y, s1));
            s2 = fmaf(S.q10[k][q], o.x, fmaf(S.q11[k][q], o.y, s2));
        }
        sc[t] = make_float2(s1, s2);
        __syncthreads();
    }
    float2 e = (t == 0) ? make_float2(0.f, 0.f) : sc[t - 1];
    float p1 = e.x, p2 = e.y;
    for (int j = 0; j < JSEG; j++) {
        int c = t * JSEG + j;
        if (c < NC) {
            int s = CORR ? (NC - 1 - c) : c;
            float2 v = f[s];
            f[s] = make_float2(p1, p2);          // carry entering logical chunk c
            float n1 = fmaf(m00, p1, fmaf(m01, p2, v.x - cg1));
            float n2 = fmaf(m10, p1, fmaf(m11, p2, v.y - cg2));
            p1 = n1; p2 = n2;
        }
    }
}

// K3 (fused): replay pass A from carry -> y; write y reversed into ybuf via
// LDS (coalesced float4); compute pass-B local states from register y
// (reverse recurrence) in-place over slot c.
__global__ __launch_bounds__(256, 4) void k_fusedA(const float* __restrict__ audio,
                                                   float2* __restrict__ fst,
                                                   float* __restrict__ ybuf, CoeffsS C) {
    __shared__ float lds[CPB * LDS_STRIDE];
    int rb = blockIdx.x, tid = threadIdx.x, b = blockIdx.y;
    int c = rb * CPB + tid;
    bool active = c < NC;
    float buf[CM];
    if (active) {
        const float* x = audio + (size_t)b * LX;
        float base = 2.0f * x[0] - x[PAD];
        load_u_fwd(x, base, c * CM, buf);
        float w1[NP], w2[NP];
#pragma unroll
        for (int q = 0; q < NP; q++) {
            float2 s0 = fst[(size_t)(b * NP + q) * NC + c];
            w1[q] = s0.x; w2[q] = s0.y;
        }
#pragma unroll
        for (int i = 0; i < CM; i++) {
            float uu = buf[i];
            float y = C.c0 * uu;
#pragma unroll
            for (int q = 0; q < NP; q++) {
                float wt = fmaf(C.a1[q], w1[q], fmaf(C.a2[q], w2[q], uu));
                y = fmaf(C.b0[q], wt, fmaf(C.b1[q], w1[q], y));
                w2[q] = w1[q]; w1[q] = wt;
            }
            buf[i] = y;                   // in-place: buf now holds y
        }
        // pass-B local states for chunk cp=NC-1-c (reverse recurrence over y).
        // c==NC-1 (cp==0): samples i<26 are pad -> input := y[LTOT-1]=buf[5].
        float base2 = buf[5];
        bool last = (c == NC - 1);
        float t1[NP], t2[NP];
#pragma unroll
        for (int q = 0; q < NP; q++) { t1[q] = 0.f; t2[q] = 0.f; }
#pragma unroll
        for (int i = 0; i < CM; i++) {
            float wv = buf[CM - 1 - i];
            if (last && i < 26) wv = base2;
#pragma unroll
            for (int q = 0; q < NP; q++) {
                float wt = fmaf(C.a1[q], t1[q], fmaf(C.a2[q], t2[q], wv));
                t2[q] = t1[q]; t1[q] = wt;
            }
        }
#pragma unroll
        for (int q = 0; q < NP; q++)
            fst[(size_t)(b * NP + q) * NC + c] = make_float2(t1[q], t2[q]);
        // stage y into LDS row (float2, stride 34 -> 2-way free)
#pragma unroll
        for (int k = 0; k < CM / 2; k++)
            *reinterpret_cast<float2*>(&lds[tid * LDS_STRIDE + 2 * k]) =
                make_float2(buf[2 * k], buf[2 * k + 1]);
    }
    __syncthreads();
    // cooperative coalesced reversed store of the block's contiguous region
    int nch = NC - rb * CPB; if (nch > CPB) nch = CPB;
    float4* ybase = reinterpret_cast<float4*>(
        ybuf + (size_t)b * LPAD + (size_t)(NC - rb * CPB - nch) * CM);
#pragma unroll
    for (int m = 0; m < 8; m++) {
        int o4 = m * CPB + tid;
        if (o4 < nch * 8) {
            int ts = nch - 1 - (o4 >> 3);
            int ih = 31 - 4 * (o4 & 7);
            float2 a  = *reinterpret_cast<const float2*>(&lds[ts * LDS_STRIDE + ih - 1]);
            float2 b2 = *reinterpret_cast<const float2*>(&lds[ts * LDS_STRIDE + ih - 3]);
            ybase[o4] = make_float4(a.y, a.x, b2.y, b2.x);
        }
    }
}

// K4: pass-B replay from carry -> final output via LDS (coalesced dword,
// per-element trim guards). carry for chunk cp is at physical slot NC-1-cp.
__global__ __launch_bounds__(256, 4) void k_applyB(const float* __restrict__ ybuf,
                                                   const float2* __restrict__ carry,
                                                   float* __restrict__ out, CoeffsS C) {
    __shared__ float lds[CPB * LDS_STRIDE];
    int rb = blockIdx.x, tid = threadIdx.x, b = blockIdx.y;
    int cp = rb * CPB + tid;
    bool active = cp < NC;
    if (active) {
        const float* yb = ybuf + (size_t)b * LPAD;
        float base = yb[26];
        float buf[CM];
#pragma unroll
        for (int m = 0; m < CM / 4; m++) {
            float4 v = *reinterpret_cast<const float4*>(yb + (size_t)cp * CM + 4 * m);
            buf[4 * m] = v.x - base; buf[4 * m + 1] = v.y - base;
            buf[4 * m + 2] = v.z - base; buf[4 * m + 3] = v.w - base;
        }
        float w1[NP], w2[NP];
#pragma unroll
        for (int q = 0; q < NP; q++) {
            float2 s0 = carry[(size_t)(b * NP + q) * NC + (NC - 1 - cp)];
            w1[q] = s0.x; w2[q] = s0.y;
        }
#pragma unroll
        for (int i = 0; i < CM; i++) {
            float uu = buf[i];
            float y = C.c0 * uu;
#pragma unroll
            for (int q = 0; q < NP; q++) {
                float wt = fmaf(C.a1[q], w1[q], fmaf(C.a2[q], w2[q], uu));
                y = fmaf(C.b0[q], wt, fmaf(C.b1[q], w1[q], y));
                w2[q] = w1[q]; w1[q] = wt;
            }
            lds[tid * LDS_STRIDE + i] = y;
        }
    }
    __syncthreads();
    // out[j] = yB[t], t = rb*8192 + o, j = 262220 - t  (reverse + trim)
    int nch = NC - rb * CPB; if (nch > CPB) nch = CPB;
    float* ob = out + (size_t)b * LX;
    int J0 = (LTOT - 1 - PAD + 26) - rb * (CPB * CM);
#pragma unroll
    for (int m = 0; m < CM; m++) {
        int o = m * CPB + tid;
        if (o < nch * CM) {
            int j = J0 - o;
            if (j >= 0 && j < LX)
                ob[j] = lds[(o >> 5) * LDS_STRIDE + (o & 31)];
        }
    }
}

// Host: scipy butter(8,[500,7000]/8000,'bandpass') -> poles/residues (f64),
// folded to real 2nd-order sections + 2x2 chunk-transition matrices.
static void compute_coeffs(CoeffsS& C, ScanS& S) {
    using cd = std::complex<double>;
    const int N = 8;
    const double sr = 16000.0, lo = 500.0, hi = 7000.0, fs = 2.0;
    double w0 = 2.0 * fs * std::tan(M_PI * (2.0 * lo / sr) / fs);
    double w1 = 2.0 * fs * std::tan(M_PI * (2.0 * hi / sr) / fs);
    double bw = w1 - w0, wo = std::sqrt(w0 * w1);
    cd pbp[16];
    for (int k = 0; k < N; k++) {
        int m = -N + 1 + 2 * k;
        cd pl = -std::exp(cd(0.0, M_PI * m / (2.0 * N)));
        pl *= bw / 2.0;
        cd s = std::sqrt(pl * pl - cd(wo * wo, 0.0));
        pbp[k] = pl + s; pbp[k + N] = pl - s;
    }
    double kbp = std::pow(bw, (double)N);
    const double fs2 = 4.0;
    cd pd[16], denom = 1.0;
    for (int i = 0; i < 16; i++) {
        pd[i] = (cd(fs2, 0.0) + pbp[i]) / (cd(fs2, 0.0) - pbp[i]);
        denom *= (cd(fs2, 0.0) - pbp[i]);
    }
    double kd = kbp * std::real(cd(std::pow(fs2, 8.0), 0.0) / denom);
    cd prodp = 1.0;
    for (int i = 0; i < 16; i++) prodp *= pd[i];
    cd c0 = cd(kd, 0.0) / prodp;
    int n = 0;
    for (int i = 0; i < 16; i++) {
        if (pd[i].imag() <= 0.0) continue;
        cd inv = 1.0 / pd[i];
        cd t1 = cd(1.0, 0.0) - inv, t2 = cd(1.0, 0.0) + inv;
        cd numr = cd(kd, 0.0);
        for (int k = 0; k < 8; k++) numr *= t1;
        for (int k = 0; k < 8; k++) numr *= t2;
        cd den = 1.0;
        for (int j = 0; j < 16; j++)
            if (j != i) den *= (cd(1.0, 0.0) - pd[j] * inv);
        cd r2 = 2.0 * numr / den;     // conjugate pair folded (2x residue)
        if (n < NP) {
            double a1 = 2.0 * pd[i].real();
            double a2 = -std::norm(pd[i]);
            C.a1[n] = (float)a1; C.a2[n] = (float)a2;
            C.b0[n] = (float)r2.real();
            C.b1[n] = (float)(-(r2.real() * pd[i].real() + r2.imag() * pd[i].imag()));
            // chunk transition: basis responses over CM zero-input steps
            double aw1 = 1.0, aw2 = 0.0, bw1 = 0.0, bw2 = 1.0, gw1 = 0.0, gw2 = 0.0;
            for (int k = 0; k < CM; k++) {
                double at = a1 * aw1 + a2 * aw2; aw2 = aw1; aw1 = at;
                double bt = a1 * bw1 + a2 * bw2; bw2 = bw1; bw1 = bt;
                double gt = a1 * gw1 + a2 * gw2 + 1.0; gw2 = gw1; gw1 = gt;
            }
            double M[4] = { aw1, bw1, aw2, bw2 };   // [m00 m01; m10 m11]
            S.m00[n] = (float)M[0]; S.m01[n] = (float)M[1];
            S.m10[n] = (float)M[2]; S.m11[n] = (float)M[3];
            S.g1[n] = (float)gw1;   S.g2[n] = (float)gw2;
            // Q_0 = M^JSEG; Q_{k+1} = Q_k^2
            double Q[4] = { 1.0, 0.0, 0.0, 1.0 };
            for (int k = 0; k < JSEG; k++) {
                double q0 = Q[0] * M[0] + Q[1] * M[2], q1 = Q[0] * M[1] + Q[1] * M[3];
                double q2 = Q[2] * M[0] + Q[3] * M[2], q3 = Q[2] * M[1] + Q[3] * M[3];
                Q[0] = q0; Q[1] = q1; Q[2] = q2; Q[3] = q3;
            }
            for (int k = 0; k < 8; k++) {
                S.q00[k][n] = (float)Q[0]; S.q01[k][n] = (float)Q[1];
                S.q10[k][n] = (float)Q[2]; S.q11[k][n] = (float)Q[3];
                double q0 = Q[0] * Q[0] + Q[1] * Q[2], q1 = Q[0] * Q[1] + Q[1] * Q[3];
                double q2 = Q[2] * Q[0] + Q[3] * Q[2], q3 = Q[2] * Q[1] + Q[3] * Q[3];
                Q[0] = q0; Q[1] = q1; Q[2] = q2; Q[3] = q3;
            }
            n++;
        }
    }
    C.c0 = (float)c0.real();
}

extern "C" void kernel_launch(void* const* d_in, const int* in_sizes, int n_in,
                              void* d_out, int out_size, void* d_ws, size_t ws_size,
                              hipStream_t stream) {
    const float* audio = (const float*)d_in[0];
    float* out = (float*)d_out;

    CoeffsS C; ScanS S;
    compute_coeffs(C, S);

    // ws: ybuf (NB*LPAD f32, 33.57MB) + fst (256*NC float2, 16.79MB; holds
    // statesA -> carryA -> statesB -> carryB in-place). Total 50.36MB.
    char* ws = (char*)d_ws;
    size_t ybytes = (size_t)NB * LPAD * sizeof(float);
    float*  ybuf = (float*)ws;
    float2* fst  = (float2*)(ws + ybytes);

    dim3 blk(256), g(BPR, NB), gs(NB * NP);

    k_statesA<<<g,  blk, 0, stream>>>(audio, fst, C);
    k_scan<0> <<<gs, blk, 0, stream>>>(fst, ybuf, S);
    k_fusedA  <<<g,  blk, 0, stream>>>(audio, fst, ybuf, C);
    k_scan<1> <<<gs, blk, 0, stream>>>(fst, ybuf, S);
    k_applyB  <<<g,  blk, 0, stream>>>(ybuf, fst, out, C);
}